// Round 1
// baseline (632.099 us; speedup 1.0000x reference)
//
#include <hip/hip_runtime.h>
#include <hip/hip_bf16.h>

// Problem constants (match reference file)
#define B_   2
#define S_   2048
#define D_   512
#define H_   8
#define DK_  64
#define FF_  2048
#define EPS_ 1e-3f

// ---------------------------------------------------------------------------
// Pad-mask: xm[b,s,:] = x[b,s,:] * (s < lengths[b])
// ---------------------------------------------------------------------------
__global__ __launch_bounds__(256) void mask_kernel(const float* __restrict__ x,
                                                   const int* __restrict__ lengths,
                                                   float* __restrict__ xm) {
  const int idx = blockIdx.x * 256 + threadIdx.x;  // one float4 per thread
  const int d4 = D_ / 4;                           // 128
  const int s = (idx / d4) & (S_ - 1);
  const int b = idx / (d4 * S_);
  float4 v = reinterpret_cast<const float4*>(x)[idx];
  if (s >= lengths[b]) { v.x = 0.f; v.y = 0.f; v.z = 0.f; v.w = 0.f; }
  reinterpret_cast<float4*>(xm)[idx] = v;
}

// ---------------------------------------------------------------------------
// fp32 tiled GEMM: C = A(MxK) @ B(KxN) + bias [+ res] [relu]
// 64x64 tile, BK=16, 256 threads, 4x4 microtile/thread.
// LDS rows padded to 68 floats: keeps float4 16B alignment and makes the
// compute-phase reads broadcast/2-way (free per m136).
// ---------------------------------------------------------------------------
enum { EPI_BIAS = 0, EPI_BIAS_RES = 1, EPI_BIAS_RELU = 2 };

template <int EPI>
__global__ __launch_bounds__(256) void gemm_kernel(const float* __restrict__ A,
                                                   const float* __restrict__ Bw,
                                                   const float* __restrict__ bias,
                                                   const float* __restrict__ res,
                                                   float* __restrict__ C,
                                                   int M, int N, int K) {
  __shared__ float As[16][68];  // As[k][m] (A tile transposed)
  __shared__ float Bs[16][68];  // Bs[k][n]
  const int t  = threadIdx.x;
  const int tx = t & 15, ty = t >> 4;
  const int m0 = blockIdx.y * 64, n0 = blockIdx.x * 64;
  const int ar = t >> 2, ak = (t & 3) << 2;   // A-load: row 0..63, k-quad
  const int br = t >> 4, bc = (t & 15) << 2;  // B-load: k-row 0..15, col-quad

  float acc[4][4] = {};

  for (int k0 = 0; k0 < K; k0 += 16) {
    float4 a4 = *reinterpret_cast<const float4*>(A + (size_t)(m0 + ar) * K + k0 + ak);
    As[ak + 0][ar] = a4.x;
    As[ak + 1][ar] = a4.y;
    As[ak + 2][ar] = a4.z;
    As[ak + 3][ar] = a4.w;
    *reinterpret_cast<float4*>(&Bs[br][bc]) =
        *reinterpret_cast<const float4*>(Bw + (size_t)(k0 + br) * N + n0 + bc);
    __syncthreads();
#pragma unroll
    for (int k = 0; k < 16; ++k) {
      const float4 av = *reinterpret_cast<const float4*>(&As[k][ty * 4]);
      const float4 bv = *reinterpret_cast<const float4*>(&Bs[k][tx * 4]);
      const float a_[4] = {av.x, av.y, av.z, av.w};
      const float b_[4] = {bv.x, bv.y, bv.z, bv.w};
#pragma unroll
      for (int ii = 0; ii < 4; ++ii)
#pragma unroll
        for (int jj = 0; jj < 4; ++jj)
          acc[ii][jj] = fmaf(a_[ii], b_[jj], acc[ii][jj]);
    }
    __syncthreads();
  }

  const float4 bias4 = *reinterpret_cast<const float4*>(bias + n0 + tx * 4);
#pragma unroll
  for (int ii = 0; ii < 4; ++ii) {
    const int row = m0 + ty * 4 + ii;
    float4 o;
    o.x = acc[ii][0] + bias4.x;
    o.y = acc[ii][1] + bias4.y;
    o.z = acc[ii][2] + bias4.z;
    o.w = acc[ii][3] + bias4.w;
    if constexpr (EPI == EPI_BIAS_RES) {
      const float4 r4 = *reinterpret_cast<const float4*>(res + (size_t)row * N + n0 + tx * 4);
      o.x += r4.x; o.y += r4.y; o.z += r4.z; o.w += r4.w;
    }
    if constexpr (EPI == EPI_BIAS_RELU) {
      o.x = fmaxf(o.x, 0.f); o.y = fmaxf(o.y, 0.f);
      o.z = fmaxf(o.z, 0.f); o.w = fmaxf(o.w, 0.f);
    }
    *reinterpret_cast<float4*>(C + (size_t)row * N + n0 + tx * 4) = o;
  }
}

// ---------------------------------------------------------------------------
// Diagonal attention: for each (b,h,i) compute online-softmax row stats
// (max m, sum l) over allowed keys j in [0, min(i, len-1)] and the diagonal
// numerator exp(s_ii - m); then wgt[b,i,h,:] = (diag/l) * v[b,i,h,:].
// One workgroup (256 thr) per (b,h, 64-query block). Scores NOT scaled by
// 1/sqrt(dk) (matches reference). Keys with i>=len give diag=0.
// ---------------------------------------------------------------------------
__global__ __launch_bounds__(256) void attn_diag_kernel(const float* __restrict__ q,
                                                        const float* __restrict__ k,
                                                        const float* __restrict__ v,
                                                        const int* __restrict__ lengths,
                                                        float* __restrict__ wgt) {
  __shared__ float Qs[64][68];  // Qs[row][d]
  __shared__ float Kt[64][68];  // Kt[d][j]  (transposed -> conflict-free reads)
  __shared__ float sm[64], sl[64], sd[64];

  const int t  = threadIdx.x;
  const int tx = t & 15, ty = t >> 4;
  const int bh = blockIdx.y;
  const int b = bh >> 3, h = bh & 7;
  const int i0 = blockIdx.x * 64;
  const int len = lengths[b];

  {  // load Q tile (64 rows x 64 dims)
    const int r_ = t >> 4, quad = t & 15;
#pragma unroll
    for (int it = 0; it < 4; ++it) {
      const int r = it * 16 + r_;
      *reinterpret_cast<float4*>(&Qs[r][quad * 4]) = *reinterpret_cast<const float4*>(
          q + (size_t)(b * S_ + i0 + r) * D_ + h * DK_ + quad * 4);
    }
  }
  if (t < 64) { sm[t] = -1e30f; sl[t] = 0.f; sd[t] = 0.f; }

  const int jlimit = min(i0 + 63, len - 1);  // last key column any row here needs
  for (int j0 = 0; j0 <= jlimit; j0 += 64) {
    {  // load K tile transposed
      const int r_ = t >> 4, quad = t & 15;
#pragma unroll
      for (int it = 0; it < 4; ++it) {
        const int r = it * 16 + r_;
        const float4 k4 = *reinterpret_cast<const float4*>(
            k + (size_t)(b * S_ + j0 + r) * D_ + h * DK_ + quad * 4);
        Kt[quad * 4 + 0][r] = k4.x;
        Kt[quad * 4 + 1][r] = k4.y;
        Kt[quad * 4 + 2][r] = k4.z;
        Kt[quad * 4 + 3][r] = k4.w;
      }
    }
    __syncthreads();

    float s[4][4] = {};
#pragma unroll 4
    for (int d = 0; d < 64; ++d) {
      float qa[4], kb[4];
#pragma unroll
      for (int ii = 0; ii < 4; ++ii) qa[ii] = Qs[ty * 4 + ii][d];
#pragma unroll
      for (int jj = 0; jj < 4; ++jj) kb[jj] = Kt[d][tx * 4 + jj];
#pragma unroll
      for (int ii = 0; ii < 4; ++ii)
#pragma unroll
        for (int jj = 0; jj < 4; ++jj)
          s[ii][jj] = fmaf(qa[ii], kb[jj], s[ii][jj]);
    }

    // online softmax row-stats update (row state is wave-local: ty in [0,4) per wave)
#pragma unroll
    for (int ii = 0; ii < 4; ++ii) {
      const int il = ty * 4 + ii;
      const int ig = i0 + il;
      float mx = -1e30f;
#pragma unroll
      for (int jj = 0; jj < 4; ++jj) {
        const int j = j0 + tx * 4 + jj;
        if (j > ig || j >= len) s[ii][jj] = -1e30f;  // mask
        mx = fmaxf(mx, s[ii][jj]);
      }
#pragma unroll
      for (int off = 1; off < 16; off <<= 1) mx = fmaxf(mx, __shfl_xor(mx, off));
      const float mold = sm[il];
      const float mnew = fmaxf(mold, mx);
      float ps = 0.f, pd = 0.f;
#pragma unroll
      for (int jj = 0; jj < 4; ++jj) {
        const int j = j0 + tx * 4 + jj;
        const float e = expf(s[ii][jj] - mnew);  // masked -> exp(-1e30-m) == 0
        ps += e;
        if (j == ig) pd = e;  // diagonal numerator (0 if masked)
      }
#pragma unroll
      for (int off = 1; off < 16; off <<= 1) {
        ps += __shfl_xor(ps, off);
        pd += __shfl_xor(pd, off);
      }
      if (tx == 0) {
        const float scale = expf(mold - mnew);
        sl[il] = sl[il] * scale + ps;
        sd[il] = sd[il] * scale + pd;
        sm[il] = mnew;
      }
    }
    __syncthreads();
  }

  {  // epilogue: wgt = diag * v
    const int r_ = t >> 4, quad = t & 15;
#pragma unroll
    for (int it = 0; it < 4; ++it) {
      const int r = it * 16 + r_;
      const int ig = i0 + r;
      float dg = 0.f;
      if (ig < len) dg = sd[r] / sl[r];  // l > 0 guaranteed (key 0 always valid)
      const size_t off = (size_t)(b * S_ + ig) * D_ + h * DK_ + quad * 4;
      float4 v4 = *reinterpret_cast<const float4*>(v + off);
      v4.x *= dg; v4.y *= dg; v4.z *= dg; v4.w *= dg;
      *reinterpret_cast<float4*>(wgt + off) = v4;
    }
  }
}

// ---------------------------------------------------------------------------
// LayerNorm over last dim (D=512), biased variance, eps inside sqrt.
// One 256-thread block per row; 2 floats per thread.
// ---------------------------------------------------------------------------
__global__ __launch_bounds__(256) void ln_kernel(const float* __restrict__ X,
                                                 const float* __restrict__ gamma,
                                                 const float* __restrict__ beta,
                                                 float* __restrict__ Y) {
  const int row = blockIdx.x;
  const int t = threadIdx.x;
  const float* x = X + (size_t)row * D_;
  const float2 xv = *reinterpret_cast<const float2*>(x + t * 2);
  float s = xv.x + xv.y;
  float s2 = xv.x * xv.x + xv.y * xv.y;
#pragma unroll
  for (int off = 1; off < 64; off <<= 1) {
    s += __shfl_xor(s, off);
    s2 += __shfl_xor(s2, off);
  }
  __shared__ float red[8];
  const int w = t >> 6;
  if ((t & 63) == 0) { red[w] = s; red[4 + w] = s2; }
  __syncthreads();
  const float ts  = red[0] + red[1] + red[2] + red[3];
  const float ts2 = red[4] + red[5] + red[6] + red[7];
  const float mean = ts * (1.f / D_);
  const float var  = ts2 * (1.f / D_) - mean * mean;
  const float inv  = 1.f / sqrtf(var + EPS_);
  const float2 g  = *reinterpret_cast<const float2*>(gamma + t * 2);
  const float2 bt = *reinterpret_cast<const float2*>(beta + t * 2);
  float2 o;
  o.x = g.x * ((xv.x - mean) * inv) + bt.x;
  o.y = g.y * ((xv.y - mean) * inv) + bt.y;
  *reinterpret_cast<float2*>(Y + (size_t)row * D_ + t * 2) = o;
}

// ---------------------------------------------------------------------------
extern "C" void kernel_launch(void* const* d_in, const int* in_sizes, int n_in,
                              void* d_out, int out_size, void* d_ws, size_t ws_size,
                              hipStream_t stream) {
  const float* x       = (const float*)d_in[0];
  const int*   lengths = (const int*)d_in[1];
  const float* Wq = (const float*)d_in[2];
  const float* bq = (const float*)d_in[3];
  const float* Wk = (const float*)d_in[4];
  const float* bk = (const float*)d_in[5];
  const float* Wv = (const float*)d_in[6];
  const float* bv = (const float*)d_in[7];
  const float* Wo = (const float*)d_in[8];
  const float* bo = (const float*)d_in[9];
  const float* W1 = (const float*)d_in[10];
  const float* b1 = (const float*)d_in[11];
  const float* W2 = (const float*)d_in[12];
  const float* b2 = (const float*)d_in[13];
  const float* gamma1 = (const float*)d_in[14];
  const float* beta1  = (const float*)d_in[15];
  const float* gamma2 = (const float*)d_in[16];
  const float* beta2  = (const float*)d_in[17];
  float* out = (float*)d_out;

  float* ws = (float*)d_ws;
  const size_t NT = (size_t)B_ * S_ * D_;  // 2,097,152 floats
  // Buffer plan (8*NT floats = 64 MB total), with reuse:
  float* xm  = ws + 0 * NT;  // masked x          (dead after o-proj)
  float* qb  = ws + 1 * NT;  // Q                 (dead after attention)
  float* kb_ = ws + 2 * NT;  // K                 (dead after attention)
  float* vb  = ws + 3 * NT;  // V                 (dead after attention)
  float* wgt = ws + 4 * NT;  // diag*V            (dead after o-proj)
  float* h1  = ws + 2 * NT;  // xm + attn_out     (reuses K slot)
  float* y1  = ws + 3 * NT;  // LN1 out           (reuses V slot)
  float* ff1 = ws + 4 * NT;  // relu(y1@W1+b1), 4*NT floats (reuses wgt slot)
  float* h2  = ws + 0 * NT;  // y1 + ff2          (reuses xm slot)

  const dim3 blk(256);
  const int M = B_ * S_;  // 4096

  mask_kernel<<<dim3((B_ * S_ * D_ / 4) / 256), blk, 0, stream>>>(x, lengths, xm);

  gemm_kernel<EPI_BIAS><<<dim3(D_ / 64, M / 64), blk, 0, stream>>>(xm, Wq, bq, nullptr, qb, M, D_, D_);
  gemm_kernel<EPI_BIAS><<<dim3(D_ / 64, M / 64), blk, 0, stream>>>(xm, Wk, bk, nullptr, kb_, M, D_, D_);
  gemm_kernel<EPI_BIAS><<<dim3(D_ / 64, M / 64), blk, 0, stream>>>(xm, Wv, bv, nullptr, vb, M, D_, D_);

  attn_diag_kernel<<<dim3(S_ / 64, B_ * H_), blk, 0, stream>>>(qb, kb_, vb, lengths, wgt);

  gemm_kernel<EPI_BIAS_RES><<<dim3(D_ / 64, M / 64), blk, 0, stream>>>(wgt, Wo, bo, xm, h1, M, D_, D_);
  ln_kernel<<<dim3(M), blk, 0, stream>>>(h1, gamma1, beta1, y1);

  gemm_kernel<EPI_BIAS_RELU><<<dim3(FF_ / 64, M / 64), blk, 0, stream>>>(y1, W1, b1, nullptr, ff1, M, FF_, D_);
  gemm_kernel<EPI_BIAS_RES><<<dim3(D_ / 64, M / 64), blk, 0, stream>>>(ff1, W2, b2, y1, h2, M, D_, FF_);
  ln_kernel<<<dim3(M), blk, 0, stream>>>(h2, gamma2, beta2, out);
}

// Round 3
// 404.623 us; speedup vs baseline: 1.5622x; 1.5622x over previous
//
#include <hip/hip_runtime.h>

// Problem constants (match reference file)
#define B_   2
#define S_   2048
#define D_   512
#define H_   8
#define DK_  64
#define FF_  2048
#define EPS_ 1e-3f
#define QS_  1536   // fused QKV row stride

typedef __bf16 bf16;
typedef __bf16 bf16x4 __attribute__((ext_vector_type(4)));
typedef __bf16 bf16x8 __attribute__((ext_vector_type(8)));
typedef float  f32x4  __attribute__((ext_vector_type(4)));

// ---------------------------------------------------------------------------
// Weight transpose + hi/lo bf16 split:  W[K][N] -> T{hi,lo}[rowOff+n][k]
// (B-operand wants k-contiguous rows so MFMA B-fragments are single b128 reads)
// ---------------------------------------------------------------------------
struct Trans4Args {
  const float* w[4];
  bf16* thi[4];
  bf16* tlo[4];
  int rowOff[4];
};

__global__ __launch_bounds__(256) void transpose4_kernel(Trans4Args a) {
  // all four weights are 512x512; grid (16,16,4)
  __shared__ float tl[32][33];
  const int t = threadIdx.x;
  const int tx = t & 31, ty = t >> 5;  // 32 x 8
  const int n0 = blockIdx.x * 32, k0 = blockIdx.y * 32;
  const int wsel = blockIdx.z;
  const float* __restrict__ W = a.w[wsel];
#pragma unroll
  for (int r = 0; r < 32; r += 8)
    tl[r + ty][tx] = W[(size_t)(k0 + r + ty) * 512 + n0 + tx];
  __syncthreads();
  bf16* __restrict__ Thi = a.thi[wsel];
  bf16* __restrict__ Tlo = a.tlo[wsel];
  const int ro = a.rowOff[wsel];
#pragma unroll
  for (int r = 0; r < 32; r += 8) {
    const int n = r + ty;
    const float v = tl[tx][n];  // stride-33 -> conflict-free
    const bf16 h = (bf16)v;
    const size_t o = (size_t)(ro + n0 + n) * 512 + k0 + tx;
    Thi[o] = h;
    Tlo[o] = (bf16)(v - (float)h);
  }
}

__global__ __launch_bounds__(256) void transpose_split_kernel(
    const float* __restrict__ W, int K, int N,
    bf16* __restrict__ Thi, bf16* __restrict__ Tlo) {
  __shared__ float tl[32][33];
  const int t = threadIdx.x;
  const int tx = t & 31, ty = t >> 5;
  const int n0 = blockIdx.x * 32, k0 = blockIdx.y * 32;
#pragma unroll
  for (int r = 0; r < 32; r += 8)
    tl[r + ty][tx] = W[(size_t)(k0 + r + ty) * N + n0 + tx];
  __syncthreads();
#pragma unroll
  for (int r = 0; r < 32; r += 8) {
    const int n = r + ty;
    const float v = tl[tx][n];
    const bf16 h = (bf16)v;
    const size_t o = (size_t)(n0 + n) * K + k0 + tx;
    Thi[o] = h;
    Tlo[o] = (bf16)(v - (float)h);
  }
}

__global__ __launch_bounds__(256) void pack_bias_kernel(const float* __restrict__ bq,
                                                        const float* __restrict__ bk,
                                                        const float* __restrict__ bv,
                                                        float* __restrict__ out) {
  const int i = blockIdx.x * 256 + threadIdx.x;  // 0..1535
  out[i] = (i < 512) ? bq[i] : (i < 1024) ? bk[i - 512] : bv[i - 1024];
}

// ---------------------------------------------------------------------------
// Pad-mask + hi/lo split: xm = x * (s < len) stored as bf16 hi/lo pair
// ---------------------------------------------------------------------------
__global__ __launch_bounds__(256) void mask_split_kernel(const float* __restrict__ x,
                                                         const int* __restrict__ lengths,
                                                         bf16* __restrict__ xhi,
                                                         bf16* __restrict__ xlo) {
  const int idx = blockIdx.x * 256 + threadIdx.x;  // one float4 per thread
  const int d4 = D_ / 4;
  const int s = (idx / d4) & (S_ - 1);
  const int b = idx / (d4 * S_);
  float4 v = reinterpret_cast<const float4*>(x)[idx];
  if (s >= lengths[b]) { v.x = 0.f; v.y = 0.f; v.z = 0.f; v.w = 0.f; }
  const float vv[4] = {v.x, v.y, v.z, v.w};
  bf16x4 h, l;
#pragma unroll
  for (int c = 0; c < 4; ++c) {
    const bf16 hh = (bf16)vv[c];
    h[c] = hh;
    l[c] = (bf16)(vv[c] - (float)hh);
  }
  reinterpret_cast<bf16x4*>(xhi)[idx] = h;
  reinterpret_cast<bf16x4*>(xlo)[idx] = l;
}

// ---------------------------------------------------------------------------
// Split-bf16 MFMA GEMM: C = (Ahi+Alo)(Bhi+Blo)^T' + bias [+res][relu][mask-res]
//   A{hi,lo}: [M][K] bf16 row-major;  B{hi,lo}: [N][K] bf16 row-major (pre-T).
//   Tile 128x64, BK=32, 256 thr (4 waves as 2x2, each 64x32).
//   3 MFMA products per acc (hi*hi + hi*lo + lo*hi) ~ fp32 accuracy.
// MFMA 16x16x32 lane mapping: A/B frag lane l = [l&15][(l>>4)*8 + j];
// D frag lane l reg r = [ (l>>4)*4 + r ][ l&15 ]  (m89/m91-verified).
// ---------------------------------------------------------------------------
enum { EPI_BIAS = 0, EPI_BIAS_RES = 1, EPI_BIAS_RELU = 2, EPI_BIAS_RES_MASK = 3 };

template <int EPI, bool SPLIT>
__global__ __launch_bounds__(256) void gemm_kernel(
    const bf16* __restrict__ Ahi, const bf16* __restrict__ Alo,
    const bf16* __restrict__ Bhi, const bf16* __restrict__ Blo,
    const float* __restrict__ bias, const float* __restrict__ res,
    const int* __restrict__ lengths,
    float* __restrict__ C, bf16* __restrict__ Chi, bf16* __restrict__ Clo,
    int K, int ldc) {
  // rows padded to 40 bf16 (80 B = 5x16B): frag reads stay 16B-aligned and
  // land <=2-way per bank (free per m136)
  __shared__ __align__(16) bf16 As[2][128][40];
  __shared__ __align__(16) bf16 Bs[2][64][40];
  const int t = threadIdx.x;
  const int m0 = blockIdx.y * 128, n0 = blockIdx.x * 64;
  const int ar = t >> 1, ak = (t & 1) * 16;  // A staging: row, k-offset (2x16B)
  const int br = t >> 2, bk = (t & 3) * 8;   // B staging: row, k-offset (1x16B)
  const int lane = t & 63, wv = t >> 6;
  const int wm = (wv >> 1) * 64, wn = (wv & 1) * 32;
  const int fr = lane & 15, fg = lane >> 4;

  f32x4 acc[4][2] = {};

  const bf16* pAhi = Ahi + (size_t)(m0 + ar) * K + ak;
  const bf16* pAlo = Alo + (size_t)(m0 + ar) * K + ak;
  const bf16* pBhi = Bhi + (size_t)(n0 + br) * K + bk;
  const bf16* pBlo = Blo + (size_t)(n0 + br) * K + bk;

  for (int k0 = 0; k0 < K; k0 += 32) {
    *reinterpret_cast<int4*>(&As[0][ar][ak])     = *reinterpret_cast<const int4*>(pAhi + k0);
    *reinterpret_cast<int4*>(&As[0][ar][ak + 8]) = *reinterpret_cast<const int4*>(pAhi + k0 + 8);
    *reinterpret_cast<int4*>(&As[1][ar][ak])     = *reinterpret_cast<const int4*>(pAlo + k0);
    *reinterpret_cast<int4*>(&As[1][ar][ak + 8]) = *reinterpret_cast<const int4*>(pAlo + k0 + 8);
    *reinterpret_cast<int4*>(&Bs[0][br][bk])     = *reinterpret_cast<const int4*>(pBhi + k0);
    *reinterpret_cast<int4*>(&Bs[1][br][bk])     = *reinterpret_cast<const int4*>(pBlo + k0);
    __syncthreads();

    bf16x8 ah[4], al[4], bh[2], bl[2];
#pragma unroll
    for (int m = 0; m < 4; ++m) {
      ah[m] = *reinterpret_cast<const bf16x8*>(&As[0][wm + m * 16 + fr][fg * 8]);
      al[m] = *reinterpret_cast<const bf16x8*>(&As[1][wm + m * 16 + fr][fg * 8]);
    }
#pragma unroll
    for (int n = 0; n < 2; ++n) {
      bh[n] = *reinterpret_cast<const bf16x8*>(&Bs[0][wn + n * 16 + fr][fg * 8]);
      bl[n] = *reinterpret_cast<const bf16x8*>(&Bs[1][wn + n * 16 + fr][fg * 8]);
    }
#pragma unroll
    for (int m = 0; m < 4; ++m)
#pragma unroll
      for (int n = 0; n < 2; ++n) {
        acc[m][n] = __builtin_amdgcn_mfma_f32_16x16x32_bf16(ah[m], bh[n], acc[m][n], 0, 0, 0);
        acc[m][n] = __builtin_amdgcn_mfma_f32_16x16x32_bf16(ah[m], bl[n], acc[m][n], 0, 0, 0);
        acc[m][n] = __builtin_amdgcn_mfma_f32_16x16x32_bf16(al[m], bh[n], acc[m][n], 0, 0, 0);
      }
    __syncthreads();
  }

  // epilogue
  int lenb = 0;
  if constexpr (EPI == EPI_BIAS_RES_MASK) lenb = lengths[m0 >> 11];  // 128-row tile sits in one batch
  float bcol[2];
#pragma unroll
  for (int n = 0; n < 2; ++n) bcol[n] = bias[n0 + wn + n * 16 + fr];
#pragma unroll
  for (int m = 0; m < 4; ++m)
#pragma unroll
    for (int n = 0; n < 2; ++n) {
      const int col = n0 + wn + n * 16 + fr;
#pragma unroll
      for (int r = 0; r < 4; ++r) {
        const int row = m0 + wm + m * 16 + fg * 4 + r;
        float v = acc[m][n][r] + bcol[n];
        if constexpr (EPI == EPI_BIAS_RES) v += res[(size_t)row * ldc + col];
        if constexpr (EPI == EPI_BIAS_RES_MASK) {
          const int s = row & (S_ - 1);
          if (s < lenb) v += res[(size_t)row * D_ + col];  // res = raw x, masked inline
        }
        if constexpr (EPI == EPI_BIAS_RELU) v = fmaxf(v, 0.f);
        const size_t o = (size_t)row * ldc + col;
        if constexpr (SPLIT) {
          const bf16 h = (bf16)v;
          Chi[o] = h;
          Clo[o] = (bf16)(v - (float)h);
        } else {
          C[o] = v;
        }
      }
    }
}

// ---------------------------------------------------------------------------
// Diagonal attention v2: per (b,h,64-row block) compute online-softmax row
// stats over allowed keys + diagonal numerator; write wgt = (diag/l)*v as
// bf16 hi/lo (O-proj input). Row-major Ks (bank-even staging), microtile
// remap i=ii*16+ty (Q broadcast), j=jj*16+tx (2-way = free). Row state in
// registers (redundant across the 16 tx lanes). No 1/sqrt(dk) (ref-faithful).
// ---------------------------------------------------------------------------
__global__ __launch_bounds__(256) void attn_diag_kernel(const float* __restrict__ qkv,
                                                        const int* __restrict__ lengths,
                                                        bf16* __restrict__ whi,
                                                        bf16* __restrict__ wlo) {
  __shared__ __align__(16) float Qs[64][68];
  __shared__ __align__(16) float Ks[64][68];
  const int t = threadIdx.x;
  const int tx = t & 15, ty = t >> 4;
  const int bh = blockIdx.y;
  const int bb = bh >> 3, h = bh & 7;
  const int i0 = (31 - (int)blockIdx.x) * 64;  // longest-first for tail packing
  const int len = lengths[bb];

  if (i0 >= len) {  // fully padded block: wgt = 0 (branch is block-uniform)
    bf16x4 z = {};
#pragma unroll
    for (int ii = 0; ii < 4; ++ii) {
      const int ig = i0 + ii * 16 + ty;
      const size_t o = (size_t)(bb * S_ + ig) * D_ + h * DK_ + tx * 4;
      *reinterpret_cast<bf16x4*>(&whi[o]) = z;
      *reinterpret_cast<bf16x4*>(&wlo[o]) = z;
    }
    return;
  }

  {  // stage Q tile (row-major, coalesced, bank-even)
    const int r_ = t >> 4, quad = t & 15;
#pragma unroll
    for (int it = 0; it < 4; ++it) {
      const int r = it * 16 + r_;
      *reinterpret_cast<float4*>(&Qs[r][quad * 4]) = *reinterpret_cast<const float4*>(
          qkv + (size_t)(bb * S_ + i0 + r) * QS_ + h * DK_ + quad * 4);
    }
  }

  float m_r[4], l_r[4], d_r[4];
#pragma unroll
  for (int ii = 0; ii < 4; ++ii) { m_r[ii] = -1e30f; l_r[ii] = 0.f; d_r[ii] = 0.f; }

  const int jlim = min(i0 + 63, len - 1);
  for (int j0 = 0; j0 <= jlim; j0 += 64) {
    {  // stage K tile row-major
      const int r_ = t >> 4, quad = t & 15;
#pragma unroll
      for (int it = 0; it < 4; ++it) {
        const int r = it * 16 + r_;
        *reinterpret_cast<float4*>(&Ks[r][quad * 4]) = *reinterpret_cast<const float4*>(
            qkv + (size_t)(bb * S_ + j0 + r) * QS_ + D_ + h * DK_ + quad * 4);
      }
    }
    __syncthreads();

    float sc[4][4] = {};
#pragma unroll 4
    for (int d0 = 0; d0 < 64; d0 += 4) {
      float4 qv[4], kv[4];
#pragma unroll
      for (int ii = 0; ii < 4; ++ii) qv[ii] = *reinterpret_cast<const float4*>(&Qs[ii * 16 + ty][d0]);
#pragma unroll
      for (int jj = 0; jj < 4; ++jj) kv[jj] = *reinterpret_cast<const float4*>(&Ks[jj * 16 + tx][d0]);
#pragma unroll
      for (int ii = 0; ii < 4; ++ii)
#pragma unroll
        for (int jj = 0; jj < 4; ++jj) {
          sc[ii][jj] = fmaf(qv[ii].x, kv[jj].x, sc[ii][jj]);
          sc[ii][jj] = fmaf(qv[ii].y, kv[jj].y, sc[ii][jj]);
          sc[ii][jj] = fmaf(qv[ii].z, kv[jj].z, sc[ii][jj]);
          sc[ii][jj] = fmaf(qv[ii].w, kv[jj].w, sc[ii][jj]);
        }
    }

#pragma unroll
    for (int ii = 0; ii < 4; ++ii) {
      const int ig = i0 + ii * 16 + ty;
      float mx = -1e30f;
#pragma unroll
      for (int jj = 0; jj < 4; ++jj) {
        const int j = j0 + jj * 16 + tx;
        if (j > ig || j >= len) sc[ii][jj] = -1e30f;  // causal + padding mask
        mx = fmaxf(mx, sc[ii][jj]);
      }
#pragma unroll
      for (int off = 1; off < 16; off <<= 1) mx = fmaxf(mx, __shfl_xor(mx, off));
      const float mnew = fmaxf(m_r[ii], mx);  // finite: key j=0 always valid at tile 0
      float ps = 0.f, pd = 0.f;
#pragma unroll
      for (int jj = 0; jj < 4; ++jj) {
        const int j = j0 + jj * 16 + tx;
        const float e = __expf(sc[ii][jj] - mnew);  // masked -> underflow to 0
        ps += e;
        if (j == ig) pd = e;  // diagonal numerator
      }
#pragma unroll
      for (int off = 1; off < 16; off <<= 1) {
        ps += __shfl_xor(ps, off);
        pd += __shfl_xor(pd, off);
      }
      const float scale = __expf(m_r[ii] - mnew);
      l_r[ii] = l_r[ii] * scale + ps;
      d_r[ii] = d_r[ii] * scale + pd;
      m_r[ii] = mnew;
    }
    __syncthreads();
  }

  // epilogue: wgt = (diag/l) * v, split to bf16 hi/lo
#pragma unroll
  for (int ii = 0; ii < 4; ++ii) {
    const int ig = i0 + ii * 16 + ty;
    float dg = 0.f;
    if (ig < len) dg = d_r[ii] / l_r[ii];  // padded rows: diag weight = 0
    const float4 v4 = *reinterpret_cast<const float4*>(
        qkv + (size_t)(bb * S_ + ig) * QS_ + 2 * D_ + h * DK_ + tx * 4);
    const float vv[4] = {dg * v4.x, dg * v4.y, dg * v4.z, dg * v4.w};
    bf16x4 hh, ll;
#pragma unroll
    for (int c = 0; c < 4; ++c) {
      const bf16 x = (bf16)vv[c];
      hh[c] = x;
      ll[c] = (bf16)(vv[c] - (float)x);
    }
    const size_t o = (size_t)(bb * S_ + ig) * D_ + h * DK_ + tx * 4;
    *reinterpret_cast<bf16x4*>(&whi[o]) = hh;
    *reinterpret_cast<bf16x4*>(&wlo[o]) = ll;
  }
}

// ---------------------------------------------------------------------------
// LayerNorm over last dim (D=512); optional fused bf16 hi/lo split output.
// ---------------------------------------------------------------------------
template <bool SPLIT>
__global__ __launch_bounds__(256) void ln_kernel(const float* __restrict__ X,
                                                 const float* __restrict__ gamma,
                                                 const float* __restrict__ beta,
                                                 float* __restrict__ Y,
                                                 bf16* __restrict__ Yhi,
                                                 bf16* __restrict__ Ylo) {
  const int row = blockIdx.x;
  const int t = threadIdx.x;
  const float* x = X + (size_t)row * D_;
  const float2 xv = *reinterpret_cast<const float2*>(x + t * 2);
  float s = xv.x + xv.y;
  float s2 = xv.x * xv.x + xv.y * xv.y;
#pragma unroll
  for (int off = 1; off < 64; off <<= 1) {
    s += __shfl_xor(s, off);
    s2 += __shfl_xor(s2, off);
  }
  __shared__ float red[8];
  const int w = t >> 6;
  if ((t & 63) == 0) { red[w] = s; red[4 + w] = s2; }
  __syncthreads();
  const float ts  = red[0] + red[1] + red[2] + red[3];
  const float ts2 = red[4] + red[5] + red[6] + red[7];
  const float mean = ts * (1.f / D_);
  const float var  = ts2 * (1.f / D_) - mean * mean;
  const float inv  = 1.f / sqrtf(var + EPS_);
  const float2 g  = *reinterpret_cast<const float2*>(gamma + t * 2);
  const float2 bt = *reinterpret_cast<const float2*>(beta + t * 2);
  float2 o;
  o.x = g.x * ((xv.x - mean) * inv) + bt.x;
  o.y = g.y * ((xv.y - mean) * inv) + bt.y;
  *reinterpret_cast<float2*>(Y + (size_t)row * D_ + t * 2) = o;
  if constexpr (SPLIT) {
    const bf16 hx = (bf16)o.x, hy = (bf16)o.y;
    const size_t oo = (size_t)row * D_ + t * 2;
    Yhi[oo] = hx;
    Yhi[oo + 1] = hy;
    Ylo[oo] = (bf16)(o.x - (float)hx);
    Ylo[oo + 1] = (bf16)(o.y - (float)hy);
  }
}

// ---------------------------------------------------------------------------
extern "C" void kernel_launch(void* const* d_in, const int* in_sizes, int n_in,
                              void* d_out, int out_size, void* d_ws, size_t ws_size,
                              hipStream_t stream) {
  const float* x       = (const float*)d_in[0];
  const int*   lengths = (const int*)d_in[1];
  const float* Wq = (const float*)d_in[2];
  const float* bq = (const float*)d_in[3];
  const float* Wk = (const float*)d_in[4];
  const float* bk = (const float*)d_in[5];
  const float* Wv = (const float*)d_in[6];
  const float* bv = (const float*)d_in[7];
  const float* Wo = (const float*)d_in[8];
  const float* bo = (const float*)d_in[9];
  const float* W1 = (const float*)d_in[10];
  const float* b1 = (const float*)d_in[11];
  const float* W2 = (const float*)d_in[12];
  const float* b2 = (const float*)d_in[13];
  const float* gamma1 = (const float*)d_in[14];
  const float* beta1  = (const float*)d_in[15];
  const float* gamma2 = (const float*)d_in[16];
  const float* beta2  = (const float*)d_in[17];
  float* out = (float*)d_out;

  char* ws = (char*)d_ws;
  // ---- workspace layout (lifetime-overlapped, total 62,920,704 B < 64 MB) ----
  bf16*  qkvT_hi = (bf16*)(ws + 0);          // [1536][512]
  bf16*  qkvT_lo = (bf16*)(ws + 1572864);
  bf16*  WoT_hi  = (bf16*)(ws + 3145728);    // [512][512]
  bf16*  WoT_lo  = (bf16*)(ws + 3670016);
  bf16*  W1T_hi  = (bf16*)(ws + 4194304);    // [2048][512]
  bf16*  W1T_lo  = (bf16*)(ws + 6291456);
  bf16*  W2T_hi  = (bf16*)(ws + 8388608);    // [512][2048]
  bf16*  W2T_lo  = (bf16*)(ws + 10485760);
  float* bqkv    = (float*)(ws + 12582912);  // [1536]
  // region A: qkv f32 (25.2MB) + h1 (8.4MB)  -->  later ff1_hi/lo (2x16.8MB)
  float* qkv_f32 = (float*)(ws + 12589056);  // [4096][1536]
  float* h1      = (float*)(ws + 37754880);  // [4096][512]
  bf16*  ff1_hi  = (bf16*)(ws + 12589056);   // [4096][2048]
  bf16*  ff1_lo  = (bf16*)(ws + 29366272);
  // region B: xm_hi/lo --> y1_hi/lo --> h2
  bf16*  xm_hi   = (bf16*)(ws + 46143488);   // [4096][512]
  bf16*  xm_lo   = (bf16*)(ws + 50337792);
  bf16*  y1_hi   = (bf16*)(ws + 46143488);
  bf16*  y1_lo   = (bf16*)(ws + 50337792);
  float* h2      = (float*)(ws + 46143488);  // [4096][512]
  // region C: wgt_hi/lo --> y1 f32
  bf16*  wgt_hi  = (bf16*)(ws + 54532096);   // [4096][512]
  bf16*  wgt_lo  = (bf16*)(ws + 58726400);
  float* y1      = (float*)(ws + 54532096);  // [4096][512]

  const dim3 blk(256);
  const int M = B_ * S_;  // 4096

  // 1) weight transposes + hi/lo splits (per-launch; weights are small)
  Trans4Args ta;
  ta.w[0] = Wq; ta.w[1] = Wk; ta.w[2] = Wv; ta.w[3] = Wo;
  ta.thi[0] = qkvT_hi; ta.thi[1] = qkvT_hi; ta.thi[2] = qkvT_hi; ta.thi[3] = WoT_hi;
  ta.tlo[0] = qkvT_lo; ta.tlo[1] = qkvT_lo; ta.tlo[2] = qkvT_lo; ta.tlo[3] = WoT_lo;
  ta.rowOff[0] = 0; ta.rowOff[1] = 512; ta.rowOff[2] = 1024; ta.rowOff[3] = 0;
  transpose4_kernel<<<dim3(16, 16, 4), blk, 0, stream>>>(ta);
  transpose_split_kernel<<<dim3(64, 16), blk, 0, stream>>>(W1, 512, 2048, W1T_hi, W1T_lo);
  transpose_split_kernel<<<dim3(16, 64), blk, 0, stream>>>(W2, 2048, 512, W2T_hi, W2T_lo);
  pack_bias_kernel<<<dim3(6), blk, 0, stream>>>(bq, bk, bv, bqkv);

  // 2) mask + split
  mask_split_kernel<<<dim3((M * D_ / 4) / 256), blk, 0, stream>>>(x, lengths, xm_hi, xm_lo);

  // 3) fused QKV GEMM -> qkv_f32 [M][1536]
  gemm_kernel<EPI_BIAS, false><<<dim3(QS_ / 64, M / 128), blk, 0, stream>>>(
      xm_hi, xm_lo, qkvT_hi, qkvT_lo, bqkv, nullptr, nullptr,
      qkv_f32, nullptr, nullptr, 512, QS_);

  // 4) diagonal attention -> wgt hi/lo
  attn_diag_kernel<<<dim3(S_ / 64, B_ * H_), blk, 0, stream>>>(qkv_f32, lengths, wgt_hi, wgt_lo);

  // 5) O-proj + masked-x residual -> h1
  gemm_kernel<EPI_BIAS_RES_MASK, false><<<dim3(D_ / 64, M / 128), blk, 0, stream>>>(
      wgt_hi, wgt_lo, WoT_hi, WoT_lo, bo, x, lengths,
      h1, nullptr, nullptr, 512, D_);

  // 6) LN1 -> y1 f32 + y1 hi/lo
  ln_kernel<true><<<dim3(M), blk, 0, stream>>>(h1, gamma1, beta1, y1, y1_hi, y1_lo);

  // 7) FF1 (+relu) -> ff1 hi/lo
  gemm_kernel<EPI_BIAS_RELU, true><<<dim3(FF_ / 64, M / 128), blk, 0, stream>>>(
      y1_hi, y1_lo, W1T_hi, W1T_lo, b1, nullptr, nullptr,
      nullptr, ff1_hi, ff1_lo, 512, FF_);

  // 8) FF2 + y1 residual -> h2
  gemm_kernel<EPI_BIAS_RES, false><<<dim3(D_ / 64, M / 128), blk, 0, stream>>>(
      ff1_hi, ff1_lo, W2T_hi, W2T_lo, b2, y1, nullptr,
      h2, nullptr, nullptr, FF_, D_);

  // 9) LN2 -> out
  ln_kernel<false><<<dim3(M), blk, 0, stream>>>(h2, gamma2, beta2, out, nullptr, nullptr);
}

// Round 4
// 331.869 us; speedup vs baseline: 1.9047x; 1.2192x over previous
//
#include <hip/hip_runtime.h>

// Problem constants (match reference file)
#define B_   2
#define S_   2048
#define D_   512
#define H_   8
#define DK_  64
#define FF_  2048
#define EPS_ 1e-3f
#define QS_  1536   // fused QKV row stride

typedef __bf16 bf16;
typedef __bf16 bf16x4 __attribute__((ext_vector_type(4)));
typedef __bf16 bf16x8 __attribute__((ext_vector_type(8)));
typedef float  f32x4  __attribute__((ext_vector_type(4)));

// ---------------------------------------------------------------------------
// Weight transpose + hi/lo bf16 split:  W[K][N] -> T{hi,lo}[rowOff+n][k]
// ---------------------------------------------------------------------------
struct Trans4Args {
  const float* w[4];
  bf16* thi[4];
  bf16* tlo[4];
  int rowOff[4];
};

__global__ __launch_bounds__(256) void transpose4_kernel(Trans4Args a) {
  __shared__ float tl[32][33];
  const int t = threadIdx.x;
  const int tx = t & 31, ty = t >> 5;  // 32 x 8
  const int n0 = blockIdx.x * 32, k0 = blockIdx.y * 32;
  const int wsel = blockIdx.z;
  const float* __restrict__ W = a.w[wsel];
#pragma unroll
  for (int r = 0; r < 32; r += 8)
    tl[r + ty][tx] = W[(size_t)(k0 + r + ty) * 512 + n0 + tx];
  __syncthreads();
  bf16* __restrict__ Thi = a.thi[wsel];
  bf16* __restrict__ Tlo = a.tlo[wsel];
  const int ro = a.rowOff[wsel];
#pragma unroll
  for (int r = 0; r < 32; r += 8) {
    const int n = r + ty;
    const float v = tl[tx][n];  // stride-33 -> conflict-free
    const bf16 h = (bf16)v;
    const size_t o = (size_t)(ro + n0 + n) * 512 + k0 + tx;
    Thi[o] = h;
    Tlo[o] = (bf16)(v - (float)h);
  }
}

__global__ __launch_bounds__(256) void transpose_split_kernel(
    const float* __restrict__ W, int K, int N,
    bf16* __restrict__ Thi, bf16* __restrict__ Tlo) {
  __shared__ float tl[32][33];
  const int t = threadIdx.x;
  const int tx = t & 31, ty = t >> 5;
  const int n0 = blockIdx.x * 32, k0 = blockIdx.y * 32;
#pragma unroll
  for (int r = 0; r < 32; r += 8)
    tl[r + ty][tx] = W[(size_t)(k0 + r + ty) * N + n0 + tx];
  __syncthreads();
#pragma unroll
  for (int r = 0; r < 32; r += 8) {
    const int n = r + ty;
    const float v = tl[tx][n];
    const bf16 h = (bf16)v;
    const size_t o = (size_t)(n0 + n) * K + k0 + tx;
    Thi[o] = h;
    Tlo[o] = (bf16)(v - (float)h);
  }
}

__global__ __launch_bounds__(256) void pack_bias_kernel(const float* __restrict__ bq,
                                                        const float* __restrict__ bk,
                                                        const float* __restrict__ bv,
                                                        float* __restrict__ out) {
  const int i = blockIdx.x * 256 + threadIdx.x;  // 0..1535
  out[i] = (i < 512) ? bq[i] : (i < 1024) ? bk[i - 512] : bv[i - 1024];
}

// ---------------------------------------------------------------------------
// Pad-mask + hi/lo split
// ---------------------------------------------------------------------------
__global__ __launch_bounds__(256) void mask_split_kernel(const float* __restrict__ x,
                                                         const int* __restrict__ lengths,
                                                         bf16* __restrict__ xhi,
                                                         bf16* __restrict__ xlo) {
  const int idx = blockIdx.x * 256 + threadIdx.x;
  const int d4 = D_ / 4;
  const int s = (idx / d4) & (S_ - 1);
  const int b = idx / (d4 * S_);
  float4 v = reinterpret_cast<const float4*>(x)[idx];
  if (s >= lengths[b]) { v.x = 0.f; v.y = 0.f; v.z = 0.f; v.w = 0.f; }
  const float vv[4] = {v.x, v.y, v.z, v.w};
  bf16x4 h, l;
#pragma unroll
  for (int c = 0; c < 4; ++c) {
    const bf16 hh = (bf16)vv[c];
    h[c] = hh;
    l[c] = (bf16)(vv[c] - (float)hh);
  }
  reinterpret_cast<bf16x4*>(xhi)[idx] = h;
  reinterpret_cast<bf16x4*>(xlo)[idx] = l;
}

// ---------------------------------------------------------------------------
// Split-bf16 MFMA GEMM, templated tile width BN in {64,128}. BM=128, BK=32,
// 256 thr = 4 waves (2x2), each wave 64 x BN/2. 3 MFMA products per acc.
// ---------------------------------------------------------------------------
enum { EPI_BIAS = 0, EPI_BIAS_RES = 1, EPI_BIAS_RELU = 2, EPI_BIAS_RES_MASK = 3 };

template <int EPI, bool SPLIT, int BN>
__global__ __launch_bounds__(256) void gemm_kernel(
    const bf16* __restrict__ Ahi, const bf16* __restrict__ Alo,
    const bf16* __restrict__ Bhi, const bf16* __restrict__ Blo,
    const float* __restrict__ bias, const float* __restrict__ res,
    const int* __restrict__ lengths,
    float* __restrict__ C, bf16* __restrict__ Chi, bf16* __restrict__ Clo,
    int K, int ldc) {
  constexpr int NW = BN / 32;  // 16-col fragment tiles per wave (n-dir)
  // rows padded to 40 bf16 (80 B = 5x16B): 16B-aligned, <=2-way bank aliasing
  __shared__ __align__(16) bf16 As[2][128][40];
  __shared__ __align__(16) bf16 Bs[2][BN][40];
  const int t = threadIdx.x;
  const int m0 = blockIdx.y * 128, n0 = blockIdx.x * BN;
  const int ar = t >> 1, ak = (t & 1) * 16;
  const int lane = t & 63, wv = t >> 6;
  const int wm = (wv >> 1) * 64, wn = (wv & 1) * (BN / 2);
  const int fr = lane & 15, fg = lane >> 4;

  f32x4 acc[4][NW] = {};

  int br, bk;
  if constexpr (BN == 64) { br = t >> 2; bk = (t & 3) * 8; }
  else                    { br = t >> 1; bk = (t & 1) * 16; }

  const bf16* pAhi = Ahi + (size_t)(m0 + ar) * K + ak;
  const bf16* pAlo = Alo + (size_t)(m0 + ar) * K + ak;
  const bf16* pBhi = Bhi + (size_t)(n0 + br) * K + bk;
  const bf16* pBlo = Blo + (size_t)(n0 + br) * K + bk;

  for (int k0 = 0; k0 < K; k0 += 32) {
    *reinterpret_cast<int4*>(&As[0][ar][ak])     = *reinterpret_cast<const int4*>(pAhi + k0);
    *reinterpret_cast<int4*>(&As[0][ar][ak + 8]) = *reinterpret_cast<const int4*>(pAhi + k0 + 8);
    *reinterpret_cast<int4*>(&As[1][ar][ak])     = *reinterpret_cast<const int4*>(pAlo + k0);
    *reinterpret_cast<int4*>(&As[1][ar][ak + 8]) = *reinterpret_cast<const int4*>(pAlo + k0 + 8);
    if constexpr (BN == 64) {
      *reinterpret_cast<int4*>(&Bs[0][br][bk]) = *reinterpret_cast<const int4*>(pBhi + k0);
      *reinterpret_cast<int4*>(&Bs[1][br][bk]) = *reinterpret_cast<const int4*>(pBlo + k0);
    } else {
      *reinterpret_cast<int4*>(&Bs[0][br][bk])     = *reinterpret_cast<const int4*>(pBhi + k0);
      *reinterpret_cast<int4*>(&Bs[0][br][bk + 8]) = *reinterpret_cast<const int4*>(pBhi + k0 + 8);
      *reinterpret_cast<int4*>(&Bs[1][br][bk])     = *reinterpret_cast<const int4*>(pBlo + k0);
      *reinterpret_cast<int4*>(&Bs[1][br][bk + 8]) = *reinterpret_cast<const int4*>(pBlo + k0 + 8);
    }
    __syncthreads();

    bf16x8 ah[4], al[4], bh[NW], bl[NW];
#pragma unroll
    for (int m = 0; m < 4; ++m) {
      ah[m] = *reinterpret_cast<const bf16x8*>(&As[0][wm + m * 16 + fr][fg * 8]);
      al[m] = *reinterpret_cast<const bf16x8*>(&As[1][wm + m * 16 + fr][fg * 8]);
    }
#pragma unroll
    for (int n = 0; n < NW; ++n) {
      bh[n] = *reinterpret_cast<const bf16x8*>(&Bs[0][wn + n * 16 + fr][fg * 8]);
      bl[n] = *reinterpret_cast<const bf16x8*>(&Bs[1][wn + n * 16 + fr][fg * 8]);
    }
#pragma unroll
    for (int m = 0; m < 4; ++m)
#pragma unroll
      for (int n = 0; n < NW; ++n) {
        acc[m][n] = __builtin_amdgcn_mfma_f32_16x16x32_bf16(ah[m], bh[n], acc[m][n], 0, 0, 0);
        acc[m][n] = __builtin_amdgcn_mfma_f32_16x16x32_bf16(ah[m], bl[n], acc[m][n], 0, 0, 0);
        acc[m][n] = __builtin_amdgcn_mfma_f32_16x16x32_bf16(al[m], bh[n], acc[m][n], 0, 0, 0);
      }
    __syncthreads();
  }

  // epilogue
  int lenb = 0;
  if constexpr (EPI == EPI_BIAS_RES_MASK) lenb = lengths[m0 >> 11];
  float bcol[NW];
#pragma unroll
  for (int n = 0; n < NW; ++n) bcol[n] = bias[n0 + wn + n * 16 + fr];
#pragma unroll
  for (int m = 0; m < 4; ++m)
#pragma unroll
    for (int n = 0; n < NW; ++n) {
      const int col = n0 + wn + n * 16 + fr;
#pragma unroll
      for (int r = 0; r < 4; ++r) {
        const int row = m0 + wm + m * 16 + fg * 4 + r;
        float v = acc[m][n][r] + bcol[n];
        if constexpr (EPI == EPI_BIAS_RES) v += res[(size_t)row * ldc + col];
        if constexpr (EPI == EPI_BIAS_RES_MASK) {
          const int s = row & (S_ - 1);
          if (s < lenb) v += res[(size_t)row * D_ + col];
        }
        if constexpr (EPI == EPI_BIAS_RELU) v = fmaxf(v, 0.f);
        const size_t o = (size_t)row * ldc + col;
        if constexpr (SPLIT) {
          const bf16 h = (bf16)v;
          Chi[o] = h;
          Clo[o] = (bf16)(v - (float)h);
        } else {
          C[o] = v;
        }
      }
    }
}

// ---------------------------------------------------------------------------
// Attention phase 1: one block per causal (i-tile64, j-chunk128) pair x (b,h).
// Computes per-row partial online-softmax stats (m, l, d) over <=2 k-tiles.
// Pair index p -> (ib, jc): triangular-ish unflatten; jc <= (ib*64+63)/128.
// Neutral rows (all keys masked in this chunk) keep m=-1e30; merge kernel
// annihilates their contribution via exp(m - mn) = 0.
// ---------------------------------------------------------------------------
__global__ __launch_bounds__(256) void attn_part_kernel(const float* __restrict__ qkv,
                                                        const int* __restrict__ lengths,
                                                        float* __restrict__ pm,
                                                        float* __restrict__ pl,
                                                        float* __restrict__ pd) {
  __shared__ __align__(16) float Qs[64][68];
  __shared__ __align__(16) float Ks[64][68];
  const int t = threadIdx.x;
  const int tx = t & 15, ty = t >> 4;
  const int bh = blockIdx.y;
  const int bb = bh >> 3, h = bh & 7;

  // unflatten p -> (ib, jc): ib=2a starts at a^2+a, ib=2a+1 starts at (a+1)^2
  const int p = blockIdx.x;
  int a = (int)sqrtf((float)p);
  while ((a + 1) * (a + 1) <= p) ++a;
  while (a * a > p) --a;
  int ib, jc;
  if (p >= a * a + a) { ib = 2 * a;     jc = p - (a * a + a); }
  else                { ib = 2 * a - 1; jc = p - a * a; }

  const int i0 = ib * 64;
  const int len = lengths[bb];
  if (i0 >= len || jc * 128 >= len) return;  // block-uniform: partials unread

  {  // stage Q tile
    const int r_ = t >> 4, quad = t & 15;
#pragma unroll
    for (int it = 0; it < 4; ++it) {
      const int r = it * 16 + r_;
      *reinterpret_cast<float4*>(&Qs[r][quad * 4]) = *reinterpret_cast<const float4*>(
          qkv + (size_t)(bb * S_ + i0 + r) * QS_ + h * DK_ + quad * 4);
    }
  }

  float m_r[4], l_r[4], d_r[4];
#pragma unroll
  for (int ii = 0; ii < 4; ++ii) { m_r[ii] = -1e30f; l_r[ii] = 0.f; d_r[ii] = 0.f; }

  const int jlim = min(i0 + 63, len - 1);
  for (int jt = 0; jt < 2; ++jt) {
    const int j0 = jc * 128 + jt * 64;
    if (j0 > jlim) break;  // uniform
    {  // stage K tile
      const int r_ = t >> 4, quad = t & 15;
#pragma unroll
      for (int it = 0; it < 4; ++it) {
        const int r = it * 16 + r_;
        *reinterpret_cast<float4*>(&Ks[r][quad * 4]) = *reinterpret_cast<const float4*>(
            qkv + (size_t)(bb * S_ + j0 + r) * QS_ + D_ + h * DK_ + quad * 4);
      }
    }
    __syncthreads();

    float sc[4][4] = {};
#pragma unroll 4
    for (int d0 = 0; d0 < 64; d0 += 4) {
      float4 qv[4], kv[4];
#pragma unroll
      for (int ii = 0; ii < 4; ++ii) qv[ii] = *reinterpret_cast<const float4*>(&Qs[ii * 16 + ty][d0]);
#pragma unroll
      for (int jj = 0; jj < 4; ++jj) kv[jj] = *reinterpret_cast<const float4*>(&Ks[jj * 16 + tx][d0]);
#pragma unroll
      for (int ii = 0; ii < 4; ++ii)
#pragma unroll
        for (int jj = 0; jj < 4; ++jj) {
          sc[ii][jj] = fmaf(qv[ii].x, kv[jj].x, sc[ii][jj]);
          sc[ii][jj] = fmaf(qv[ii].y, kv[jj].y, sc[ii][jj]);
          sc[ii][jj] = fmaf(qv[ii].z, kv[jj].z, sc[ii][jj]);
          sc[ii][jj] = fmaf(qv[ii].w, kv[jj].w, sc[ii][jj]);
        }
    }

#pragma unroll
    for (int ii = 0; ii < 4; ++ii) {
      const int ig = i0 + ii * 16 + ty;
      float mx = -1e30f;
#pragma unroll
      for (int jj = 0; jj < 4; ++jj) {
        const int j = j0 + jj * 16 + tx;
        if (j > ig || j >= len) sc[ii][jj] = -1e30f;
        mx = fmaxf(mx, sc[ii][jj]);
      }
#pragma unroll
      for (int off = 1; off < 16; off <<= 1) mx = fmaxf(mx, __shfl_xor(mx, off));
      const float mnew = fmaxf(m_r[ii], mx);
      float ps = 0.f, pdg = 0.f;
#pragma unroll
      for (int jj = 0; jj < 4; ++jj) {
        const int j = j0 + jj * 16 + tx;
        const float e = __expf(sc[ii][jj] - mnew);
        ps += e;
        if (j == ig) pdg = e;
      }
#pragma unroll
      for (int off = 1; off < 16; off <<= 1) {
        ps += __shfl_xor(ps, off);
        pdg += __shfl_xor(pdg, off);
      }
      const float scale = __expf(m_r[ii] - mnew);
      l_r[ii] = l_r[ii] * scale + ps;
      d_r[ii] = d_r[ii] * scale + pdg;
      m_r[ii] = mnew;
    }
    __syncthreads();
  }

  if (tx == 0) {  // write partials (one lane per row)
    const size_t base = ((size_t)(bh * 32 + ib) * 16 + jc) * 64;
#pragma unroll
    for (int ii = 0; ii < 4; ++ii) {
      const int row = ii * 16 + ty;
      const float mm = m_r[ii];
      const bool ok = mm > -1e29f;  // row saw >=1 valid key in this chunk
      pm[base + row] = mm;
      pl[base + row] = ok ? l_r[ii] : 0.f;
      pd[base + row] = ok ? d_r[ii] : 0.f;
    }
  }
}

// ---------------------------------------------------------------------------
// Attention phase 2: merge partials per (b,h,i-tile), write wgt=(d/l)*v bf16
// hi/lo. Grid (32 ib, 16 bh), 256 thr. Padded rows/blocks -> dg=0 -> zeros.
// ---------------------------------------------------------------------------
__global__ __launch_bounds__(256) void attn_merge_kernel(
    const float* __restrict__ qkv, const int* __restrict__ lengths,
    const float* __restrict__ pm, const float* __restrict__ pl,
    const float* __restrict__ pd, bf16* __restrict__ whi, bf16* __restrict__ wlo) {
  __shared__ float msh[4][64], lsh[4][64], dsh[4][64];
  __shared__ float dgs[64];
  const int t = threadIdx.x;
  const int ib = blockIdx.x, bh = blockIdx.y;
  const int bb = bh >> 3, h = bh & 7;
  const int i0 = ib * 64;
  const int len = lengths[bb];

  const int r = t & 63, g = t >> 6;
  float m = -1e30f, l = 0.f, d = 0.f;
  if (i0 < len) {  // else partials unread (poison-safe: dg forced 0 below)
    const int jcmax = min((i0 + 63) >> 7, (len - 1) >> 7);
    const size_t base = ((size_t)(bh * 32 + ib) * 16) * 64 + r;
    for (int jc = g; jc <= jcmax; jc += 4) {
      const size_t idx = base + (size_t)jc * 64;
      const float m2 = pm[idx], l2 = pl[idx], d2 = pd[idx];
      const float mn = fmaxf(m, m2);
      const float e1 = __expf(m - mn), e2 = __expf(m2 - mn);
      l = l * e1 + l2 * e2;
      d = d * e1 + d2 * e2;
      m = mn;
    }
  }
  msh[g][r] = m; lsh[g][r] = l; dsh[g][r] = d;
  __syncthreads();
  if (t < 64) {
    float M = msh[0][t], L = lsh[0][t], Dv = dsh[0][t];
#pragma unroll
    for (int gg = 1; gg < 4; ++gg) {
      const float m2 = msh[gg][t], l2 = lsh[gg][t], d2 = dsh[gg][t];
      const float mn = fmaxf(M, m2);
      const float e1 = __expf(M - mn), e2 = __expf(m2 - mn);
      L = L * e1 + l2 * e2;
      Dv = Dv * e1 + d2 * e2;
      M = mn;
    }
    // valid rows always have the jc=0 partial with l >= 1 -> L >= 1
    dgs[t] = (i0 + t < len) ? Dv / L : 0.f;
  }
  __syncthreads();

  const int rr = t >> 2, q = t & 3;
  const float dg = dgs[rr];
  const size_t vbase = (size_t)(bb * S_ + i0 + rr) * QS_ + 2 * D_ + h * DK_;
  const size_t obase = (size_t)(bb * S_ + i0 + rr) * D_ + h * DK_;
#pragma unroll
  for (int kk = 0; kk < 4; ++kk) {
    const int col = q * 4 + kk * 16;
    const float4 v4 = *reinterpret_cast<const float4*>(qkv + vbase + col);
    const float vv[4] = {dg * v4.x, dg * v4.y, dg * v4.z, dg * v4.w};
    bf16x4 hh, ll;
#pragma unroll
    for (int c = 0; c < 4; ++c) {
      const bf16 x = (bf16)vv[c];
      hh[c] = x;
      ll[c] = (bf16)(vv[c] - (float)x);
    }
    *reinterpret_cast<bf16x4*>(&whi[obase + col]) = hh;
    *reinterpret_cast<bf16x4*>(&wlo[obase + col]) = ll;
  }
}

// ---------------------------------------------------------------------------
// LayerNorm over last dim (D=512); optional fused bf16 hi/lo split output.
// ---------------------------------------------------------------------------
template <bool SPLIT>
__global__ __launch_bounds__(256) void ln_kernel(const float* __restrict__ X,
                                                 const float* __restrict__ gamma,
                                                 const float* __restrict__ beta,
                                                 float* __restrict__ Y,
                                                 bf16* __restrict__ Yhi,
                                                 bf16* __restrict__ Ylo) {
  const int row = blockIdx.x;
  const int t = threadIdx.x;
  const float* x = X + (size_t)row * D_;
  const float2 xv = *reinterpret_cast<const float2*>(x + t * 2);
  float s = xv.x + xv.y;
  float s2 = xv.x * xv.x + xv.y * xv.y;
#pragma unroll
  for (int off = 1; off < 64; off <<= 1) {
    s += __shfl_xor(s, off);
    s2 += __shfl_xor(s2, off);
  }
  __shared__ float red[8];
  const int w = t >> 6;
  if ((t & 63) == 0) { red[w] = s; red[4 + w] = s2; }
  __syncthreads();
  const float ts  = red[0] + red[1] + red[2] + red[3];
  const float ts2 = red[4] + red[5] + red[6] + red[7];
  const float mean = ts * (1.f / D_);
  const float var  = ts2 * (1.f / D_) - mean * mean;
  const float inv  = 1.f / sqrtf(var + EPS_);
  const float2 g  = *reinterpret_cast<const float2*>(gamma + t * 2);
  const float2 bt = *reinterpret_cast<const float2*>(beta + t * 2);
  float2 o;
  o.x = g.x * ((xv.x - mean) * inv) + bt.x;
  o.y = g.y * ((xv.y - mean) * inv) + bt.y;
  *reinterpret_cast<float2*>(Y + (size_t)row * D_ + t * 2) = o;
  if constexpr (SPLIT) {
    const bf16 hx = (bf16)o.x, hy = (bf16)o.y;
    const size_t oo = (size_t)row * D_ + t * 2;
    Yhi[oo] = hx;
    Yhi[oo + 1] = hy;
    Ylo[oo] = (bf16)(o.x - (float)hx);
    Ylo[oo + 1] = (bf16)(o.y - (float)hy);
  }
}

// ---------------------------------------------------------------------------
extern "C" void kernel_launch(void* const* d_in, const int* in_sizes, int n_in,
                              void* d_out, int out_size, void* d_ws, size_t ws_size,
                              hipStream_t stream) {
  const float* x       = (const float*)d_in[0];
  const int*   lengths = (const int*)d_in[1];
  const float* Wq = (const float*)d_in[2];
  const float* bq = (const float*)d_in[3];
  const float* Wk = (const float*)d_in[4];
  const float* bk = (const float*)d_in[5];
  const float* Wv = (const float*)d_in[6];
  const float* bv = (const float*)d_in[7];
  const float* Wo = (const float*)d_in[8];
  const float* bo = (const float*)d_in[9];
  const float* W1 = (const float*)d_in[10];
  const float* b1 = (const float*)d_in[11];
  const float* W2 = (const float*)d_in[12];
  const float* b2 = (const float*)d_in[13];
  const float* gamma1 = (const float*)d_in[14];
  const float* beta1  = (const float*)d_in[15];
  const float* gamma2 = (const float*)d_in[16];
  const float* beta2  = (const float*)d_in[17];
  float* out = (float*)d_out;

  char* ws = (char*)d_ws;
  // ---- workspace layout (lifetime-overlapped, < 64 MB) ----
  bf16*  qkvT_hi = (bf16*)(ws + 0);          // [1536][512]
  bf16*  qkvT_lo = (bf16*)(ws + 1572864);
  bf16*  WoT_hi  = (bf16*)(ws + 3145728);    // [512][512]
  bf16*  WoT_lo  = (bf16*)(ws + 3670016);
  bf16*  W1T_hi  = (bf16*)(ws + 4194304);    // [2048][512]
  bf16*  W1T_lo  = (bf16*)(ws + 6291456);
  bf16*  W2T_hi  = (bf16*)(ws + 8388608);    // [512][2048]
  bf16*  W2T_lo  = (bf16*)(ws + 10485760);
  float* bqkv    = (float*)(ws + 12582912);  // [1536]
  // region A: qkv f32 (25.2MB) + h1-slot (8.4MB) --> later ff1_hi/lo
  float* qkv_f32 = (float*)(ws + 12589056);  // [4096][1536]
  float* h1      = (float*)(ws + 37754880);  // [4096][512] (after merge)
  float* part_m  = (float*)(ws + 37754880);  // [16][32][16][64] = 2MB (attn window)
  float* part_l  = (float*)(ws + 39852032);
  float* part_d  = (float*)(ws + 41949184);  // ends 44046336 < 46143488
  bf16*  ff1_hi  = (bf16*)(ws + 12589056);   // [4096][2048]
  bf16*  ff1_lo  = (bf16*)(ws + 29366272);
  // region B: xm_hi/lo --> y1_hi/lo --> h2
  bf16*  xm_hi   = (bf16*)(ws + 46143488);   // [4096][512]
  bf16*  xm_lo   = (bf16*)(ws + 50337792);
  bf16*  y1_hi   = (bf16*)(ws + 46143488);
  bf16*  y1_lo   = (bf16*)(ws + 50337792);
  float* h2      = (float*)(ws + 46143488);
  // region C: wgt_hi/lo --> y1 f32
  bf16*  wgt_hi  = (bf16*)(ws + 54532096);   // [4096][512]
  bf16*  wgt_lo  = (bf16*)(ws + 58726400);
  float* y1      = (float*)(ws + 54532096);

  const dim3 blk(256);
  const int M = B_ * S_;  // 4096

  // 1) weight transposes + hi/lo splits
  Trans4Args ta;
  ta.w[0] = Wq; ta.w[1] = Wk; ta.w[2] = Wv; ta.w[3] = Wo;
  ta.thi[0] = qkvT_hi; ta.thi[1] = qkvT_hi; ta.thi[2] = qkvT_hi; ta.thi[3] = WoT_hi;
  ta.tlo[0] = qkvT_lo; ta.tlo[1] = qkvT_lo; ta.tlo[2] = qkvT_lo; ta.tlo[3] = WoT_lo;
  ta.rowOff[0] = 0; ta.rowOff[1] = 512; ta.rowOff[2] = 1024; ta.rowOff[3] = 0;
  transpose4_kernel<<<dim3(16, 16, 4), blk, 0, stream>>>(ta);
  transpose_split_kernel<<<dim3(64, 16), blk, 0, stream>>>(W1, 512, 2048, W1T_hi, W1T_lo);
  transpose_split_kernel<<<dim3(16, 64), blk, 0, stream>>>(W2, 2048, 512, W2T_hi, W2T_lo);
  pack_bias_kernel<<<dim3(6), blk, 0, stream>>>(bq, bk, bv, bqkv);

  // 2) mask + split
  mask_split_kernel<<<dim3((M * D_ / 4) / 256), blk, 0, stream>>>(x, lengths, xm_hi, xm_lo);

  // 3) fused QKV GEMM -> qkv_f32 [M][1536]
  gemm_kernel<EPI_BIAS, false, 128><<<dim3(QS_ / 128, M / 128), blk, 0, stream>>>(
      xm_hi, xm_lo, qkvT_hi, qkvT_lo, bqkv, nullptr, nullptr,
      qkv_f32, nullptr, nullptr, 512, QS_);

  // 4) attention: balanced partials (272 causal pairs x 16 bh) + merge
  attn_part_kernel<<<dim3(272, 16), blk, 0, stream>>>(qkv_f32, lengths, part_m, part_l, part_d);
  attn_merge_kernel<<<dim3(32, 16), blk, 0, stream>>>(qkv_f32, lengths, part_m, part_l, part_d,
                                                      wgt_hi, wgt_lo);

  // 5) O-proj + masked-x residual -> h1
  gemm_kernel<EPI_BIAS_RES_MASK, false, 64><<<dim3(D_ / 64, M / 128), blk, 0, stream>>>(
      wgt_hi, wgt_lo, WoT_hi, WoT_lo, bo, x, lengths,
      h1, nullptr, nullptr, 512, D_);

  // 6) LN1 -> y1 f32 + y1 hi/lo
  ln_kernel<true><<<dim3(M), blk, 0, stream>>>(h1, gamma1, beta1, y1, y1_hi, y1_lo);

  // 7) FF1 (+relu) -> ff1 hi/lo
  gemm_kernel<EPI_BIAS_RELU, true, 128><<<dim3(FF_ / 128, M / 128), blk, 0, stream>>>(
      y1_hi, y1_lo, W1T_hi, W1T_lo, b1, nullptr, nullptr,
      nullptr, ff1_hi, ff1_lo, 512, FF_);

  // 8) FF2 + y1 residual -> h2
  gemm_kernel<EPI_BIAS_RES, false, 64><<<dim3(D_ / 64, M / 128), blk, 0, stream>>>(
      ff1_hi, ff1_lo, W2T_hi, W2T_lo, b2, y1, nullptr,
      h2, nullptr, nullptr, FF_, D_);

  // 9) LN2 -> out
  ln_kernel<false><<<dim3(M), blk, 0, stream>>>(h2, gamma2, beta2, out, nullptr, nullptr);
}

// Round 5
// 294.440 us; speedup vs baseline: 2.1468x; 1.1271x over previous
//
#include <hip/hip_runtime.h>

// Problem constants (match reference file)
#define B_   2
#define S_   2048
#define D_   512
#define H_   8
#define DK_  64
#define FF_  2048
#define EPS_ 1e-3f
#define QS_  1536   // fused QKV row stride

typedef __bf16 bf16;
typedef __bf16 bf16x4 __attribute__((ext_vector_type(4)));
typedef __bf16 bf16x8 __attribute__((ext_vector_type(8)));
typedef float  f32x4  __attribute__((ext_vector_type(4)));

// ---------------------------------------------------------------------------
// Weight transpose + hi/lo bf16 split:  W[K][N] -> T{hi,lo}[rowOff+n][k]
// ---------------------------------------------------------------------------
struct Trans4Args {
  const float* w[4];
  bf16* thi[4];
  bf16* tlo[4];
  int rowOff[4];
};

__global__ __launch_bounds__(256) void transpose4_kernel(Trans4Args a) {
  __shared__ float tl[32][33];
  const int t = threadIdx.x;
  const int tx = t & 31, ty = t >> 5;  // 32 x 8
  const int n0 = blockIdx.x * 32, k0 = blockIdx.y * 32;
  const int wsel = blockIdx.z;
  const float* __restrict__ W = a.w[wsel];
#pragma unroll
  for (int r = 0; r < 32; r += 8)
    tl[r + ty][tx] = W[(size_t)(k0 + r + ty) * 512 + n0 + tx];
  __syncthreads();
  bf16* __restrict__ Thi = a.thi[wsel];
  bf16* __restrict__ Tlo = a.tlo[wsel];
  const int ro = a.rowOff[wsel];
#pragma unroll
  for (int r = 0; r < 32; r += 8) {
    const int n = r + ty;
    const float v = tl[tx][n];  // stride-33 -> conflict-free
    const bf16 h = (bf16)v;
    const size_t o = (size_t)(ro + n0 + n) * 512 + k0 + tx;
    Thi[o] = h;
    Tlo[o] = (bf16)(v - (float)h);
  }
}

__global__ __launch_bounds__(256) void transpose_split_kernel(
    const float* __restrict__ W, int K, int N,
    bf16* __restrict__ Thi, bf16* __restrict__ Tlo) {
  __shared__ float tl[32][33];
  const int t = threadIdx.x;
  const int tx = t & 31, ty = t >> 5;
  const int n0 = blockIdx.x * 32, k0 = blockIdx.y * 32;
#pragma unroll
  for (int r = 0; r < 32; r += 8)
    tl[r + ty][tx] = W[(size_t)(k0 + r + ty) * N + n0 + tx];
  __syncthreads();
#pragma unroll
  for (int r = 0; r < 32; r += 8) {
    const int n = r + ty;
    const float v = tl[tx][n];
    const bf16 h = (bf16)v;
    const size_t o = (size_t)(n0 + n) * K + k0 + tx;
    Thi[o] = h;
    Tlo[o] = (bf16)(v - (float)h);
  }
}

__global__ __launch_bounds__(256) void pack_bias_kernel(const float* __restrict__ bq,
                                                        const float* __restrict__ bk,
                                                        const float* __restrict__ bv,
                                                        float* __restrict__ out) {
  const int i = blockIdx.x * 256 + threadIdx.x;  // 0..1535
  out[i] = (i < 512) ? bq[i] : (i < 1024) ? bk[i - 512] : bv[i - 1024];
}

// ---------------------------------------------------------------------------
// Pad-mask + hi/lo split
// ---------------------------------------------------------------------------
__global__ __launch_bounds__(256) void mask_split_kernel(const float* __restrict__ x,
                                                         const int* __restrict__ lengths,
                                                         bf16* __restrict__ xhi,
                                                         bf16* __restrict__ xlo) {
  const int idx = blockIdx.x * 256 + threadIdx.x;
  const int d4 = D_ / 4;
  const int s = (idx / d4) & (S_ - 1);
  const int b = idx / (d4 * S_);
  float4 v = reinterpret_cast<const float4*>(x)[idx];
  if (s >= lengths[b]) { v.x = 0.f; v.y = 0.f; v.z = 0.f; v.w = 0.f; }
  const float vv[4] = {v.x, v.y, v.z, v.w};
  bf16x4 h, l;
#pragma unroll
  for (int c = 0; c < 4; ++c) {
    const bf16 hh = (bf16)vv[c];
    h[c] = hh;
    l[c] = (bf16)(vv[c] - (float)hh);
  }
  reinterpret_cast<bf16x4*>(xhi)[idx] = h;
  reinterpret_cast<bf16x4*>(xlo)[idx] = l;
}

// ---------------------------------------------------------------------------
// Split-bf16 MFMA GEMM, templated tile BM x BN in {64,128}^2. BK=32, 256 thr
// = 4 waves (2x2), wave tile (BM/2)x(BN/2). 3 MFMA products per acc.
// 1D grid + XCD-aware decode: blocks on the same XCD (bid%8, per m09 round-
// robin heuristic) get a contiguous m-panel range, n fastest -> A fetched
// ~once chip-wide instead of once per XCD. nwg must be % 8 == 0 (bijective).
// ---------------------------------------------------------------------------
enum { EPI_BIAS = 0, EPI_BIAS_RES = 1, EPI_BIAS_RELU = 2, EPI_BIAS_RES_MASK = 3 };

template <int EPI, bool SPLIT, int BM, int BN>
__global__ __launch_bounds__(256) void gemm_kernel(
    const bf16* __restrict__ Ahi, const bf16* __restrict__ Alo,
    const bf16* __restrict__ Bhi, const bf16* __restrict__ Blo,
    const float* __restrict__ bias, const float* __restrict__ res,
    const int* __restrict__ lengths,
    float* __restrict__ C, bf16* __restrict__ Chi, bf16* __restrict__ Clo,
    int K, int ldc, int nx) {
  constexpr int MR = BM / 32, NR = BN / 32;  // frags per wave (m,n)
  // rows padded to 40 bf16 (80 B = 5x16B): 16B-aligned; reads/writes spread
  // uniformly over all 32 banks (stride 20 banks, cycle 8, x4 chunk offsets)
  __shared__ __align__(16) bf16 As[2][BM][40];
  __shared__ __align__(16) bf16 Bs[2][BN][40];
  const int t = threadIdx.x;

  const int nwg = gridDim.x;
  const int chunk = nwg >> 3;
  const int virt = (blockIdx.x & 7) * chunk + (blockIdx.x >> 3);
  const int m0 = (virt / nx) * BM, n0 = (virt % nx) * BN;

  constexpr int ATH = 256 / BM;        // threads per A row
  constexpr int ACH = 32 / (8 * ATH);  // 16B chunks per thread (per hi/lo)
  const int ar = t / ATH, ak = (t % ATH) * (32 / ATH);
  constexpr int BTH = 256 / BN;
  constexpr int BCH = 32 / (8 * BTH);
  const int br = t / BTH, bk = (t % BTH) * (32 / BTH);

  const int lane = t & 63, wv = t >> 6;
  const int wm = (wv >> 1) * (BM / 2), wn = (wv & 1) * (BN / 2);
  const int fr = lane & 15, fg = lane >> 4;

  f32x4 acc[MR][NR] = {};

  const bf16* pAhi = Ahi + (size_t)(m0 + ar) * K + ak;
  const bf16* pAlo = Alo + (size_t)(m0 + ar) * K + ak;
  const bf16* pBhi = Bhi + (size_t)(n0 + br) * K + bk;
  const bf16* pBlo = Blo + (size_t)(n0 + br) * K + bk;

  for (int k0 = 0; k0 < K; k0 += 32) {
#pragma unroll
    for (int c2 = 0; c2 < ACH; ++c2) {
      *reinterpret_cast<int4*>(&As[0][ar][ak + c2 * 8]) =
          *reinterpret_cast<const int4*>(pAhi + k0 + c2 * 8);
      *reinterpret_cast<int4*>(&As[1][ar][ak + c2 * 8]) =
          *reinterpret_cast<const int4*>(pAlo + k0 + c2 * 8);
    }
#pragma unroll
    for (int c2 = 0; c2 < BCH; ++c2) {
      *reinterpret_cast<int4*>(&Bs[0][br][bk + c2 * 8]) =
          *reinterpret_cast<const int4*>(pBhi + k0 + c2 * 8);
      *reinterpret_cast<int4*>(&Bs[1][br][bk + c2 * 8]) =
          *reinterpret_cast<const int4*>(pBlo + k0 + c2 * 8);
    }
    __syncthreads();

    bf16x8 ah[MR], al[MR], bh[NR], bl[NR];
#pragma unroll
    for (int m = 0; m < MR; ++m) {
      ah[m] = *reinterpret_cast<const bf16x8*>(&As[0][wm + m * 16 + fr][fg * 8]);
      al[m] = *reinterpret_cast<const bf16x8*>(&As[1][wm + m * 16 + fr][fg * 8]);
    }
#pragma unroll
    for (int n = 0; n < NR; ++n) {
      bh[n] = *reinterpret_cast<const bf16x8*>(&Bs[0][wn + n * 16 + fr][fg * 8]);
      bl[n] = *reinterpret_cast<const bf16x8*>(&Bs[1][wn + n * 16 + fr][fg * 8]);
    }
#pragma unroll
    for (int m = 0; m < MR; ++m)
#pragma unroll
      for (int n = 0; n < NR; ++n) {
        acc[m][n] = __builtin_amdgcn_mfma_f32_16x16x32_bf16(ah[m], bh[n], acc[m][n], 0, 0, 0);
        acc[m][n] = __builtin_amdgcn_mfma_f32_16x16x32_bf16(ah[m], bl[n], acc[m][n], 0, 0, 0);
        acc[m][n] = __builtin_amdgcn_mfma_f32_16x16x32_bf16(al[m], bh[n], acc[m][n], 0, 0, 0);
      }
    __syncthreads();
  }

  // epilogue
  int lenb = 0;
  if constexpr (EPI == EPI_BIAS_RES_MASK) lenb = lengths[m0 >> 11];
  float bcol[NR];
#pragma unroll
  for (int n = 0; n < NR; ++n) bcol[n] = bias[n0 + wn + n * 16 + fr];
#pragma unroll
  for (int m = 0; m < MR; ++m)
#pragma unroll
    for (int n = 0; n < NR; ++n) {
      const int col = n0 + wn + n * 16 + fr;
#pragma unroll
      for (int r = 0; r < 4; ++r) {
        const int row = m0 + wm + m * 16 + fg * 4 + r;
        float v = acc[m][n][r] + bcol[n];
        if constexpr (EPI == EPI_BIAS_RES) v += res[(size_t)row * ldc + col];
        if constexpr (EPI == EPI_BIAS_RES_MASK) {
          const int s = row & (S_ - 1);
          if (s < lenb) v += res[(size_t)row * D_ + col];
        }
        if constexpr (EPI == EPI_BIAS_RELU) v = fmaxf(v, 0.f);
        const size_t o = (size_t)row * ldc + col;
        if constexpr (SPLIT) {
          const bf16 h = (bf16)v;
          Chi[o] = h;
          Clo[o] = (bf16)(v - (float)h);
        } else {
          C[o] = v;
        }
      }
    }
}

// ---------------------------------------------------------------------------
// Attention phase 1: one block per causal (i-tile64, j-chunk128) pair x (b,h).
// Computes per-row partial online-softmax stats (m, l, d) over <=2 k-tiles.
// ---------------------------------------------------------------------------
__global__ __launch_bounds__(256) void attn_part_kernel(const float* __restrict__ qkv,
                                                        const int* __restrict__ lengths,
                                                        float* __restrict__ pm,
                                                        float* __restrict__ pl,
                                                        float* __restrict__ pd) {
  __shared__ __align__(16) float Qs[64][68];
  __shared__ __align__(16) float Ks[64][68];
  const int t = threadIdx.x;
  const int tx = t & 15, ty = t >> 4;
  const int bh = blockIdx.y;
  const int bb = bh >> 3, h = bh & 7;

  // unflatten p -> (ib, jc): ib=2a starts at a^2+a, ib=2a+1 starts at (a+1)^2
  const int p = blockIdx.x;
  int a = (int)sqrtf((float)p);
  while ((a + 1) * (a + 1) <= p) ++a;
  while (a * a > p) --a;
  int ib, jc;
  if (p >= a * a + a) { ib = 2 * a;     jc = p - (a * a + a); }
  else                { ib = 2 * a - 1; jc = p - a * a; }

  const int i0 = ib * 64;
  const int len = lengths[bb];
  if (i0 >= len || jc * 128 >= len) return;  // block-uniform: partials unread

  {  // stage Q tile
    const int r_ = t >> 4, quad = t & 15;
#pragma unroll
    for (int it = 0; it < 4; ++it) {
      const int r = it * 16 + r_;
      *reinterpret_cast<float4*>(&Qs[r][quad * 4]) = *reinterpret_cast<const float4*>(
          qkv + (size_t)(bb * S_ + i0 + r) * QS_ + h * DK_ + quad * 4);
    }
  }

  float m_r[4], l_r[4], d_r[4];
#pragma unroll
  for (int ii = 0; ii < 4; ++ii) { m_r[ii] = -1e30f; l_r[ii] = 0.f; d_r[ii] = 0.f; }

  const int jlim = min(i0 + 63, len - 1);
  for (int jt = 0; jt < 2; ++jt) {
    const int j0 = jc * 128 + jt * 64;
    if (j0 > jlim) break;  // uniform
    {  // stage K tile
      const int r_ = t >> 4, quad = t & 15;
#pragma unroll
      for (int it = 0; it < 4; ++it) {
        const int r = it * 16 + r_;
        *reinterpret_cast<float4*>(&Ks[r][quad * 4]) = *reinterpret_cast<const float4*>(
            qkv + (size_t)(bb * S_ + j0 + r) * QS_ + D_ + h * DK_ + quad * 4);
      }
    }
    __syncthreads();

    float sc[4][4] = {};
#pragma unroll 4
    for (int d0 = 0; d0 < 64; d0 += 4) {
      float4 qv[4], kv[4];
#pragma unroll
      for (int ii = 0; ii < 4; ++ii) qv[ii] = *reinterpret_cast<const float4*>(&Qs[ii * 16 + ty][d0]);
#pragma unroll
      for (int jj = 0; jj < 4; ++jj) kv[jj] = *reinterpret_cast<const float4*>(&Ks[jj * 16 + tx][d0]);
#pragma unroll
      for (int ii = 0; ii < 4; ++ii)
#pragma unroll
        for (int jj = 0; jj < 4; ++jj) {
          sc[ii][jj] = fmaf(qv[ii].x, kv[jj].x, sc[ii][jj]);
          sc[ii][jj] = fmaf(qv[ii].y, kv[jj].y, sc[ii][jj]);
          sc[ii][jj] = fmaf(qv[ii].z, kv[jj].z, sc[ii][jj]);
          sc[ii][jj] = fmaf(qv[ii].w, kv[jj].w, sc[ii][jj]);
        }
    }

#pragma unroll
    for (int ii = 0; ii < 4; ++ii) {
      const int ig = i0 + ii * 16 + ty;
      float mx = -1e30f;
#pragma unroll
      for (int jj = 0; jj < 4; ++jj) {
        const int j = j0 + jj * 16 + tx;
        if (j > ig || j >= len) sc[ii][jj] = -1e30f;
        mx = fmaxf(mx, sc[ii][jj]);
      }
#pragma unroll
      for (int off = 1; off < 16; off <<= 1) mx = fmaxf(mx, __shfl_xor(mx, off));
      const float mnew = fmaxf(m_r[ii], mx);
      float ps = 0.f, pdg = 0.f;
#pragma unroll
      for (int jj = 0; jj < 4; ++jj) {
        const int j = j0 + jj * 16 + tx;
        const float e = __expf(sc[ii][jj] - mnew);
        ps += e;
        if (j == ig) pdg = e;
      }
#pragma unroll
      for (int off = 1; off < 16; off <<= 1) {
        ps += __shfl_xor(ps, off);
        pdg += __shfl_xor(pdg, off);
      }
      const float scale = __expf(m_r[ii] - mnew);
      l_r[ii] = l_r[ii] * scale + ps;
      d_r[ii] = d_r[ii] * scale + pdg;
      m_r[ii] = mnew;
    }
    __syncthreads();
  }

  if (tx == 0) {  // write partials (one lane per row)
    const size_t base = ((size_t)(bh * 32 + ib) * 16 + jc) * 64;
#pragma unroll
    for (int ii = 0; ii < 4; ++ii) {
      const int row = ii * 16 + ty;
      const float mm = m_r[ii];
      const bool ok = mm > -1e29f;  // row saw >=1 valid key in this chunk
      pm[base + row] = mm;
      pl[base + row] = ok ? l_r[ii] : 0.f;
      pd[base + row] = ok ? d_r[ii] : 0.f;
    }
  }
}

// ---------------------------------------------------------------------------
// Attention phase 2: merge partials per (b,h,i-tile), write wgt=(d/l)*v bf16
// ---------------------------------------------------------------------------
__global__ __launch_bounds__(256) void attn_merge_kernel(
    const float* __restrict__ qkv, const int* __restrict__ lengths,
    const float* __restrict__ pm, const float* __restrict__ pl,
    const float* __restrict__ pd, bf16* __restrict__ whi, bf16* __restrict__ wlo) {
  __shared__ float msh[4][64], lsh[4][64], dsh[4][64];
  __shared__ float dgs[64];
  const int t = threadIdx.x;
  const int ib = blockIdx.x, bh = blockIdx.y;
  const int bb = bh >> 3, h = bh & 7;
  const int i0 = ib * 64;
  const int len = lengths[bb];

  const int r = t & 63, g = t >> 6;
  float m = -1e30f, l = 0.f, d = 0.f;
  if (i0 < len) {  // else partials unread (poison-safe: dg forced 0 below)
    const int jcmax = min((i0 + 63) >> 7, (len - 1) >> 7);
    const size_t base = ((size_t)(bh * 32 + ib) * 16) * 64 + r;
    for (int jc = g; jc <= jcmax; jc += 4) {
      const size_t idx = base + (size_t)jc * 64;
      const float m2 = pm[idx], l2 = pl[idx], d2 = pd[idx];
      const float mn = fmaxf(m, m2);
      const float e1 = __expf(m - mn), e2 = __expf(m2 - mn);
      l = l * e1 + l2 * e2;
      d = d * e1 + d2 * e2;
      m = mn;
    }
  }
  msh[g][r] = m; lsh[g][r] = l; dsh[g][r] = d;
  __syncthreads();
  if (t < 64) {
    float M = msh[0][t], L = lsh[0][t], Dv = dsh[0][t];
#pragma unroll
    for (int gg = 1; gg < 4; ++gg) {
      const float m2 = msh[gg][t], l2 = lsh[gg][t], d2 = dsh[gg][t];
      const float mn = fmaxf(M, m2);
      const float e1 = __expf(M - mn), e2 = __expf(m2 - mn);
      L = L * e1 + l2 * e2;
      Dv = Dv * e1 + d2 * e2;
      M = mn;
    }
    // valid rows always have the jc=0 partial with l >= 1 -> L >= 1
    dgs[t] = (i0 + t < len) ? Dv / L : 0.f;
  }
  __syncthreads();

  const int rr = t >> 2, q = t & 3;
  const float dg = dgs[rr];
  const size_t vbase = (size_t)(bb * S_ + i0 + rr) * QS_ + 2 * D_ + h * DK_;
  const size_t obase = (size_t)(bb * S_ + i0 + rr) * D_ + h * DK_;
#pragma unroll
  for (int kk = 0; kk < 4; ++kk) {
    const int col = q * 4 + kk * 16;
    const float4 v4 = *reinterpret_cast<const float4*>(qkv + vbase + col);
    const float vv[4] = {dg * v4.x, dg * v4.y, dg * v4.z, dg * v4.w};
    bf16x4 hh, ll;
#pragma unroll
    for (int c = 0; c < 4; ++c) {
      const bf16 x = (bf16)vv[c];
      hh[c] = x;
      ll[c] = (bf16)(vv[c] - (float)x);
    }
    *reinterpret_cast<bf16x4*>(&whi[obase + col]) = hh;
    *reinterpret_cast<bf16x4*>(&wlo[obase + col]) = ll;
  }
}

// ---------------------------------------------------------------------------
// LayerNorm over last dim (D=512); optional fused bf16 hi/lo split output.
// ---------------------------------------------------------------------------
template <bool SPLIT>
__global__ __launch_bounds__(256) void ln_kernel(const float* __restrict__ X,
                                                 const float* __restrict__ gamma,
                                                 const float* __restrict__ beta,
                                                 float* __restrict__ Y,
                                                 bf16* __restrict__ Yhi,
                                                 bf16* __restrict__ Ylo) {
  const int row = blockIdx.x;
  const int t = threadIdx.x;
  const float* x = X + (size_t)row * D_;
  const float2 xv = *reinterpret_cast<const float2*>(x + t * 2);
  float s = xv.x + xv.y;
  float s2 = xv.x * xv.x + xv.y * xv.y;
#pragma unroll
  for (int off = 1; off < 64; off <<= 1) {
    s += __shfl_xor(s, off);
    s2 += __shfl_xor(s2, off);
  }
  __shared__ float red[8];
  const int w = t >> 6;
  if ((t & 63) == 0) { red[w] = s; red[4 + w] = s2; }
  __syncthreads();
  const float ts  = red[0] + red[1] + red[2] + red[3];
  const float ts2 = red[4] + red[5] + red[6] + red[7];
  const float mean = ts * (1.f / D_);
  const float var  = ts2 * (1.f / D_) - mean * mean;
  const float inv  = 1.f / sqrtf(var + EPS_);
  const float2 g  = *reinterpret_cast<const float2*>(gamma + t * 2);
  const float2 bt = *reinterpret_cast<const float2*>(beta + t * 2);
  float2 o;
  o.x = g.x * ((xv.x - mean) * inv) + bt.x;
  o.y = g.y * ((xv.y - mean) * inv) + bt.y;
  *reinterpret_cast<float2*>(Y + (size_t)row * D_ + t * 2) = o;
  if constexpr (SPLIT) {
    const bf16 hx = (bf16)o.x, hy = (bf16)o.y;
    const size_t oo = (size_t)row * D_ + t * 2;
    Yhi[oo] = hx;
    Yhi[oo + 1] = hy;
    Ylo[oo] = (bf16)(o.x - (float)hx);
    Ylo[oo + 1] = (bf16)(o.y - (float)hy);
  }
}

// ---------------------------------------------------------------------------
extern "C" void kernel_launch(void* const* d_in, const int* in_sizes, int n_in,
                              void* d_out, int out_size, void* d_ws, size_t ws_size,
                              hipStream_t stream) {
  const float* x       = (const float*)d_in[0];
  const int*   lengths = (const int*)d_in[1];
  const float* Wq = (const float*)d_in[2];
  const float* bq = (const float*)d_in[3];
  const float* Wk = (const float*)d_in[4];
  const float* bk = (const float*)d_in[5];
  const float* Wv = (const float*)d_in[6];
  const float* bv = (const float*)d_in[7];
  const float* Wo = (const float*)d_in[8];
  const float* bo = (const float*)d_in[9];
  const float* W1 = (const float*)d_in[10];
  const float* b1 = (const float*)d_in[11];
  const float* W2 = (const float*)d_in[12];
  const float* b2 = (const float*)d_in[13];
  const float* gamma1 = (const float*)d_in[14];
  const float* beta1  = (const float*)d_in[15];
  const float* gamma2 = (const float*)d_in[16];
  const float* beta2  = (const float*)d_in[17];
  float* out = (float*)d_out;

  char* ws = (char*)d_ws;
  // ---- workspace layout (lifetime-overlapped, < 64 MB) ----
  bf16*  qkvT_hi = (bf16*)(ws + 0);          // [1536][512]
  bf16*  qkvT_lo = (bf16*)(ws + 1572864);
  bf16*  WoT_hi  = (bf16*)(ws + 3145728);    // [512][512]
  bf16*  WoT_lo  = (bf16*)(ws + 3670016);
  bf16*  W1T_hi  = (bf16*)(ws + 4194304);    // [2048][512]
  bf16*  W1T_lo  = (bf16*)(ws + 6291456);
  bf16*  W2T_hi  = (bf16*)(ws + 8388608);    // [512][2048]
  bf16*  W2T_lo  = (bf16*)(ws + 10485760);
  float* bqkv    = (float*)(ws + 12582912);  // [1536]
  // region A: qkv f32 (25.2MB) + h1-slot (8.4MB) --> later ff1_hi/lo
  float* qkv_f32 = (float*)(ws + 12589056);  // [4096][1536]
  float* h1      = (float*)(ws + 37754880);  // [4096][512] (after merge)
  float* part_m  = (float*)(ws + 37754880);  // [16][32][16][64] = 2MB (attn window)
  float* part_l  = (float*)(ws + 39852032);
  float* part_d  = (float*)(ws + 41949184);  // ends 44046336 < 46143488
  bf16*  ff1_hi  = (bf16*)(ws + 12589056);   // [4096][2048]
  bf16*  ff1_lo  = (bf16*)(ws + 29366272);
  // region B: xm_hi/lo --> y1_hi/lo --> h2
  bf16*  xm_hi   = (bf16*)(ws + 46143488);   // [4096][512]
  bf16*  xm_lo   = (bf16*)(ws + 50337792);
  bf16*  y1_hi   = (bf16*)(ws + 46143488);
  bf16*  y1_lo   = (bf16*)(ws + 50337792);
  float* h2      = (float*)(ws + 46143488);
  // region C: wgt_hi/lo --> y1 f32
  bf16*  wgt_hi  = (bf16*)(ws + 54532096);   // [4096][512]
  bf16*  wgt_lo  = (bf16*)(ws + 58726400);
  float* y1      = (float*)(ws + 54532096);

  const dim3 blk(256);
  const int M = B_ * S_;  // 4096

  // 1) weight transposes + hi/lo splits
  Trans4Args ta;
  ta.w[0] = Wq; ta.w[1] = Wk; ta.w[2] = Wv; ta.w[3] = Wo;
  ta.thi[0] = qkvT_hi; ta.thi[1] = qkvT_hi; ta.thi[2] = qkvT_hi; ta.thi[3] = WoT_hi;
  ta.tlo[0] = qkvT_lo; ta.tlo[1] = qkvT_lo; ta.tlo[2] = qkvT_lo; ta.tlo[3] = WoT_lo;
  ta.rowOff[0] = 0; ta.rowOff[1] = 512; ta.rowOff[2] = 1024; ta.rowOff[3] = 0;
  transpose4_kernel<<<dim3(16, 16, 4), blk, 0, stream>>>(ta);
  transpose_split_kernel<<<dim3(64, 16), blk, 0, stream>>>(W1, 512, 2048, W1T_hi, W1T_lo);
  transpose_split_kernel<<<dim3(16, 64), blk, 0, stream>>>(W2, 2048, 512, W2T_hi, W2T_lo);
  pack_bias_kernel<<<dim3(6), blk, 0, stream>>>(bq, bk, bv, bqkv);

  // 2) mask + split
  mask_split_kernel<<<dim3((M * D_ / 4) / 256), blk, 0, stream>>>(x, lengths, xm_hi, xm_lo);

  // 3) fused QKV GEMM -> qkv_f32 [M][1536].  grid 12x32=384 (%8==0)
  gemm_kernel<EPI_BIAS, false, 128, 128><<<dim3(384), blk, 0, stream>>>(
      xm_hi, xm_lo, qkvT_hi, qkvT_lo, bqkv, nullptr, nullptr,
      qkv_f32, nullptr, nullptr, 512, QS_, 12);

  // 4) attention: balanced partials (272 causal pairs x 16 bh) + merge
  attn_part_kernel<<<dim3(272, 16), blk, 0, stream>>>(qkv_f32, lengths, part_m, part_l, part_d);
  attn_merge_kernel<<<dim3(32, 16), blk, 0, stream>>>(qkv_f32, lengths, part_m, part_l, part_d,
                                                      wgt_hi, wgt_lo);

  // 5) O-proj + masked-x residual -> h1.  grid 8x64=512
  gemm_kernel<EPI_BIAS_RES_MASK, false, 64, 64><<<dim3(512), blk, 0, stream>>>(
      wgt_hi, wgt_lo, WoT_hi, WoT_lo, bo, x, lengths,
      h1, nullptr, nullptr, 512, D_, 8);

  // 6) LN1 -> y1 f32 + y1 hi/lo
  ln_kernel<true><<<dim3(M), blk, 0, stream>>>(h1, gamma1, beta1, y1, y1_hi, y1_lo);

  // 7) FF1 (+relu) -> ff1 hi/lo.  grid 16x32=512
  gemm_kernel<EPI_BIAS_RELU, true, 128, 128><<<dim3(512), blk, 0, stream>>>(
      y1_hi, y1_lo, W1T_hi, W1T_lo, b1, nullptr, nullptr,
      nullptr, ff1_hi, ff1_lo, 512, FF_, 16);

  // 8) FF2 + y1 residual -> h2.  grid 8x64=512
  gemm_kernel<EPI_BIAS_RES, false, 64, 64><<<dim3(512), blk, 0, stream>>>(
      ff1_hi, ff1_lo, W2T_hi, W2T_lo, b2, y1, nullptr,
      h2, nullptr, nullptr, FF_, D_, 8);

  // 9) LN2 -> out
  ln_kernel<false><<<dim3(M), blk, 0, stream>>>(h2, gamma2, beta2, out, nullptr, nullptr);
}